// Round 2
// baseline (354.883 us; speedup 1.0000x reference)
//
#include <hip/hip_runtime.h>
#include <hip/hip_bf16.h>
#include <stdint.h>

static constexpr int S  = 2048;
static constexpr int NH = 16;
static constexpr int HD = 64;
static constexpr int E  = 1024;
static constexpr int BB = 2;
static constexpr int MR = BB * S;   // 4096 rows

typedef __attribute__((ext_vector_type(8))) short bf16x8;
typedef __attribute__((ext_vector_type(4))) float f32x4;

__device__ __forceinline__ unsigned short f2bf(float f) {
  union { float f; unsigned u; } v; v.f = f;
  unsigned r = v.u + 0x7fffu + ((v.u >> 16) & 1u);
  return (unsigned short)(r >> 16);
}

__device__ __forceinline__ f32x4 mfma16(bf16x8 a, bf16x8 b, f32x4 c) {
  return __builtin_amdgcn_mfma_f32_16x16x32_bf16(a, b, c, 0, 0, 0);
}

__device__ __forceinline__ void gload_lds16(const void* g, void* l) {
  __builtin_amdgcn_global_load_lds(
      (const __attribute__((address_space(1))) uint32_t*)(uintptr_t)g,
      (__attribute__((address_space(3))) uint32_t*)(uintptr_t)l,
      16, 0, 0);
}

__global__ __launch_bounds__(256) void convert_bf16(
    const float* __restrict__ in, unsigned short* __restrict__ out, int n4) {
  int i = blockIdx.x * blockDim.x + threadIdx.x;
  const int stride = gridDim.x * blockDim.x;
  for (; i < n4; i += stride) {
    float4 v = ((const float4*)in)[i];
    ushort4 o;
    o.x = f2bf(v.x); o.y = f2bf(v.y); o.z = f2bf(v.z); o.w = f2bf(v.w);
    ((ushort4*)out)[i] = o;
  }
}

// C = A @ W^T + bias.  A: MxK bf16 row-major, W: NxK bf16 row-major.
// EPI 0: scatter to Q/K (b,h,s,d) and Vt (b,h,d,s) bf16.  EPI 1: f32 out + bias.
template <int EPI>
__global__ __launch_bounds__(256) void gemm_bt(
    const unsigned short* __restrict__ A, const unsigned short* __restrict__ W,
    const float* __restrict__ bias,
    void* __restrict__ o0, void* __restrict__ o1, void* __restrict__ o2,
    int M, int N, int K) {
  __shared__ __align__(16) unsigned short As[128 * 32];
  __shared__ __align__(16) unsigned short Bs[128 * 32];
  const int tid  = threadIdx.x;
  const int lane = tid & 63;
  const int wid  = tid >> 6;
  const int wm   = wid >> 1;
  const int wn   = wid & 1;
  const int g    = lane >> 4;
  const int lq   = lane & 15;
  const int row0 = blockIdx.y * 128;
  const int col0 = blockIdx.x * 128;
  const int srow = lane >> 2;
  const int sseg = (lane & 3) * 8;

  f32x4 acc[4][4] = {};

  for (int k0 = 0; k0 < K; k0 += 32) {
    __syncthreads();
#pragma unroll
    for (int cc = 0; cc < 2; ++cc) {
      const int c = wid + cc * 4;   // 8 chunks of 1KB per operand
      gload_lds16(A + (size_t)(row0 + c * 16 + srow) * K + k0 + sseg,
                  (char*)As + c * 1024);
      gload_lds16(W + (size_t)(col0 + c * 16 + srow) * K + k0 + sseg,
                  (char*)Bs + c * 1024);
    }
    __syncthreads();
    bf16x8 af[4], bfr[4];
#pragma unroll
    for (int m = 0; m < 4; ++m)
      af[m] = *(const bf16x8*)(As + (wm * 64 + m * 16 + lq) * 32 + g * 8);
#pragma unroll
    for (int n = 0; n < 4; ++n)
      bfr[n] = *(const bf16x8*)(Bs + (wn * 64 + n * 16 + lq) * 32 + g * 8);
#pragma unroll
    for (int m = 0; m < 4; ++m)
#pragma unroll
      for (int n = 0; n < 4; ++n)
        acc[m][n] = mfma16(af[m], bfr[n], acc[m][n]);
  }

  if (EPI == 0) {
    unsigned short* Qb = (unsigned short*)o0;
    unsigned short* Kb = (unsigned short*)o1;
    unsigned short* Vt = (unsigned short*)o2;
#pragma unroll
    for (int m = 0; m < 4; ++m) {
      const int rbase = row0 + wm * 64 + m * 16 + g * 4;
#pragma unroll
      for (int n = 0; n < 4; ++n) {
        const int col = col0 + wn * 64 + n * 16 + lq;  // 0..3071
        const float bi = bias[col];
        const int three = col >> 10;
        const int rem = col & 1023;
        const int h = rem >> 6, d = rem & 63;
#pragma unroll
        for (int r = 0; r < 4; ++r) {
          const int row = rbase + r;            // = b*2048 + s
          const int bb = row >> 11, ss = row & 2047;
          const unsigned short bv = f2bf(acc[m][n][r] + bi);
          if (three == 0)
            Qb[(((size_t)(bb * NH + h)) * S + ss) * HD + d] = bv;
          else if (three == 1)
            Kb[(((size_t)(bb * NH + h)) * S + ss) * HD + d] = bv;
          else
            Vt[(((size_t)(bb * NH + h)) * HD + d) * S + ss] = bv;
        }
      }
    }
  } else {
    float* Out = (float*)o0;
#pragma unroll
    for (int m = 0; m < 4; ++m) {
      const int rbase = row0 + wm * 64 + m * 16 + g * 4;
#pragma unroll
      for (int n = 0; n < 4; ++n) {
        const int col = col0 + wn * 64 + n * 16 + lq;
        const float bi = bias[col];
#pragma unroll
        for (int r = 0; r < 4; ++r)
          Out[(size_t)(rbase + r) * N + col] = acc[m][n][r] + bi;
      }
    }
  }
}

// Flash attention, causal.  Q,K: (b,h,s,d) bf16; Vt: (b,h,d,s) bf16.
// Block: 4 waves, 64 q rows (16 per wave), KV tiles of 32.
// Out: (b, s, h, d) bf16.
__global__ __launch_bounds__(256) void attn_fwd(
    const unsigned short* __restrict__ Qb, const unsigned short* __restrict__ Kb,
    const unsigned short* __restrict__ Vt, unsigned short* __restrict__ Ao,
    const int* __restrict__ causal_p) {
  __shared__ __align__(16) unsigned short Qs[64 * 72];  // stride 144B (2-way banks)
  __shared__ __align__(16) unsigned short Ks[32 * 72];
  __shared__ __align__(16) unsigned short Vs[64 * 40];  // stride 80B
  __shared__ __align__(16) unsigned short Ps[4][16 * 40];

  const int tid = threadIdx.x, lane = tid & 63, wid = tid >> 6;
  const int g = lane >> 4, lq = lane & 15;
  const int qt = blockIdx.x;        // q tile (64 rows)
  const int bh = blockIdx.y;        // b*NH + h
  const size_t base  = (size_t)bh * S * HD;
  const int causal = *causal_p;

  // stage Q tile once: 64 rows x 64 d
  for (int i = tid; i < 512; i += 256) {
    const int r = i >> 3, sg = (i & 7) * 8;
    *(int4*)(&Qs[r * 72 + sg]) =
        *(const int4*)(&Qb[base + (size_t)(qt * 64 + r) * HD + sg]);
  }

  float mM[4], lS[4];
  f32x4 accO[4] = {};
#pragma unroll
  for (int r = 0; r < 4; ++r) { mM[r] = -1e30f; lS[r] = 0.f; }

  const int nkt = causal ? (2 * qt + 2) : (S / 32);
  for (int kt = 0; kt < nkt; ++kt) {
    __syncthreads();
    {  // stage K tile (32 x 64) and Vt tile (64 x 32)
      const int r = tid >> 3, sg = (tid & 7) * 8;
      *(int4*)(&Ks[r * 72 + sg]) =
          *(const int4*)(&Kb[base + (size_t)(kt * 32 + r) * HD + sg]);
      const int vr = tid >> 2, vsg = (tid & 3) * 8;
      *(int4*)(&Vs[vr * 40 + vsg]) =
          *(const int4*)(&Vt[base + (size_t)vr * S + kt * 32 + vsg]);
    }
    __syncthreads();

    // QK^T: scores D[q][k], q = g*4+r rows, k-col = kn*16+lq
    bf16x8 qf[2], kf[2][2];
#pragma unroll
    for (int ds = 0; ds < 2; ++ds)
      qf[ds] = *(const bf16x8*)(&Qs[(wid * 16 + lq) * 72 + ds * 32 + g * 8]);
#pragma unroll
    for (int kn = 0; kn < 2; ++kn)
#pragma unroll
      for (int ds = 0; ds < 2; ++ds)
        kf[kn][ds] = *(const bf16x8*)(&Ks[(kn * 16 + lq) * 72 + ds * 32 + g * 8]);
    f32x4 sc[2] = {};
#pragma unroll
    for (int kn = 0; kn < 2; ++kn)
#pragma unroll
      for (int ds = 0; ds < 2; ++ds)
        sc[kn] = mfma16(qf[ds], kf[kn][ds], sc[kn]);

    // online softmax per q-row (r); row lives on 16 lanes sharing (g,r)
#pragma unroll
    for (int r = 0; r < 4; ++r) {
      const int q = qt * 64 + wid * 16 + g * 4 + r;
      float s0 = sc[0][r] * 0.125f;
      float s1 = sc[1][r] * 0.125f;
      if (causal) {
        if (kt * 32 + lq > q)      s0 = -1e30f;
        if (kt * 32 + 16 + lq > q) s1 = -1e30f;
      }
      float mx = fmaxf(s0, s1);
#pragma unroll
      for (int off = 1; off < 16; off <<= 1)
        mx = fmaxf(mx, __shfl_xor(mx, off));
      const float mnew = fmaxf(mM[r], mx);
      const float alpha = __expf(mM[r] - mnew);
      const float p0 = __expf(s0 - mnew);
      const float p1 = __expf(s1 - mnew);
      float rs = p0 + p1;
#pragma unroll
      for (int off = 1; off < 16; off <<= 1)
        rs += __shfl_xor(rs, off);
      lS[r] = lS[r] * alpha + rs;
      mM[r] = mnew;
#pragma unroll
      for (int dn = 0; dn < 4; ++dn) accO[dn][r] *= alpha;
      Ps[wid][(g * 4 + r) * 40 + lq]      = f2bf(p0);
      Ps[wid][(g * 4 + r) * 40 + 16 + lq] = f2bf(p1);
    }

    // PV: O[q][d] += P (16x32) @ V (32x16 per dn)
    const bf16x8 pf = *(const bf16x8*)(&Ps[wid][lq * 40 + g * 8]);
#pragma unroll
    for (int dn = 0; dn < 4; ++dn) {
      const bf16x8 vf = *(const bf16x8*)(&Vs[(dn * 16 + lq) * 40 + g * 8]);
      accO[dn] = mfma16(pf, vf, accO[dn]);
    }
  }

  // normalize + write (b, s, h, d)
  const int bb = bh >> 4, h = bh & 15;
#pragma unroll
  for (int dn = 0; dn < 4; ++dn) {
#pragma unroll
    for (int r = 0; r < 4; ++r) {
      const int q = qt * 64 + wid * 16 + g * 4 + r;
      const int d = dn * 16 + lq;
      const float o = accO[dn][r] / lS[r];
      Ao[(((size_t)bb * S + q) * NH + h) * HD + d] = f2bf(o);
    }
  }
}

extern "C" void kernel_launch(void* const* d_in, const int* in_sizes, int n_in,
                              void* d_out, int out_size, void* d_ws, size_t ws_size,
                              hipStream_t stream) {
  const float* x     = (const float*)d_in[0];
  const float* w_qkv = (const float*)d_in[1];
  const float* b_qkv = (const float*)d_in[2];
  const float* w_out = (const float*)d_in[3];
  const float* b_out = (const float*)d_in[4];
  const int*   causal = (const int*)d_in[5];

  char* ws = (char*)d_ws;
  unsigned short* xb    = (unsigned short*)(ws);              //  8 MB
  unsigned short* wqkvb = (unsigned short*)(ws + 8388608);    //  6 MB
  unsigned short* wob   = (unsigned short*)(ws + 14680064);   //  2 MB
  unsigned short* Qb    = (unsigned short*)(ws + 16777216);   //  8 MB
  unsigned short* Kb    = (unsigned short*)(ws + 25165824);   //  8 MB
  unsigned short* Vtb   = (unsigned short*)(ws + 33554432);   //  8 MB
  unsigned short* attnb = (unsigned short*)(ws + 41943040);   //  8 MB (ends 48MB)

  convert_bf16<<<1024, 256, 0, stream>>>(x, xb, (BB * S * E) / 4);
  convert_bf16<<<1024, 256, 0, stream>>>(w_qkv, wqkvb, (3 * E * E) / 4);
  convert_bf16<<<512, 256, 0, stream>>>(w_out, wob, (E * E) / 4);

  gemm_bt<0><<<dim3(3 * E / 128, MR / 128), 256, 0, stream>>>(
      xb, wqkvb, b_qkv, Qb, Kb, Vtb, MR, 3 * E, E);

  attn_fwd<<<dim3(S / 64, BB * NH), 256, 0, stream>>>(Qb, Kb, Vtb, attnb, causal);

  gemm_bt<1><<<dim3(E / 128, MR / 128), 256, 0, stream>>>(
      attnb, wob, b_out, d_out, nullptr, nullptr, MR, E, E);
}

// Round 3
// 258.834 us; speedup vs baseline: 1.3711x; 1.3711x over previous
//
#include <hip/hip_runtime.h>
#include <hip/hip_bf16.h>
#include <stdint.h>

static constexpr int S  = 2048;
static constexpr int NH = 16;
static constexpr int HD = 64;
static constexpr int E  = 1024;
static constexpr int BB = 2;
static constexpr int MR = BB * S;   // 4096 rows

typedef __attribute__((ext_vector_type(8))) short bf16x8;
typedef __attribute__((ext_vector_type(4))) float f32x4;
typedef __attribute__((ext_vector_type(16))) float f32x16;

__device__ __forceinline__ unsigned short f2bf(float f) {
  union { float f; unsigned u; } v; v.f = f;
  unsigned r = v.u + 0x7fffu + ((v.u >> 16) & 1u);
  return (unsigned short)(r >> 16);
}

__device__ __forceinline__ unsigned cvt_pk_bf16(float lo, float hi) {
  unsigned r;
  asm("v_cvt_pk_bf16_f32 %0, %1, %2" : "=v"(r) : "v"(lo), "v"(hi));
  return r;
}

__device__ __forceinline__ f32x4 mfma16(bf16x8 a, bf16x8 b, f32x4 c) {
  return __builtin_amdgcn_mfma_f32_16x16x32_bf16(a, b, c, 0, 0, 0);
}
__device__ __forceinline__ f32x16 mfma32(bf16x8 a, bf16x8 b, f32x16 c) {
  return __builtin_amdgcn_mfma_f32_32x32x16_bf16(a, b, c, 0, 0, 0);
}

__device__ __forceinline__ void gload_lds16(const void* g, void* l) {
  __builtin_amdgcn_global_load_lds(
      (const __attribute__((address_space(1))) uint32_t*)(uintptr_t)g,
      (__attribute__((address_space(3))) uint32_t*)(uintptr_t)l,
      16, 0, 0);
}

__global__ __launch_bounds__(256) void convert_bf16(
    const float* __restrict__ in, unsigned short* __restrict__ out, int n4) {
  int i = blockIdx.x * blockDim.x + threadIdx.x;
  const int stride = gridDim.x * blockDim.x;
  for (; i < n4; i += stride) {
    float4 v = ((const float4*)in)[i];
    ushort4 o;
    o.x = f2bf(v.x); o.y = f2bf(v.y); o.z = f2bf(v.z); o.w = f2bf(v.w);
    ((ushort4*)out)[i] = o;
  }
}

// C = A @ W^T + bias.  A: MxK bf16 row-major, W: NxK bf16 row-major.
template <int EPI>
__global__ __launch_bounds__(256) void gemm_bt(
    const unsigned short* __restrict__ A, const unsigned short* __restrict__ W,
    const float* __restrict__ bias,
    void* __restrict__ o0, void* __restrict__ o1, void* __restrict__ o2,
    int M, int N, int K) {
  __shared__ __align__(16) unsigned short As[128 * 32];
  __shared__ __align__(16) unsigned short Bs[128 * 32];
  const int tid  = threadIdx.x;
  const int lane = tid & 63;
  const int wid  = tid >> 6;
  const int wm   = wid >> 1;
  const int wn   = wid & 1;
  const int g    = lane >> 4;
  const int lq   = lane & 15;
  const int row0 = blockIdx.y * 128;
  const int col0 = blockIdx.x * 128;
  const int srow = lane >> 2;
  const int sseg = (lane & 3) * 8;

  f32x4 acc[4][4] = {};

  for (int k0 = 0; k0 < K; k0 += 32) {
    __syncthreads();
#pragma unroll
    for (int cc = 0; cc < 2; ++cc) {
      const int c = wid + cc * 4;
      gload_lds16(A + (size_t)(row0 + c * 16 + srow) * K + k0 + sseg,
                  (char*)As + c * 1024);
      gload_lds16(W + (size_t)(col0 + c * 16 + srow) * K + k0 + sseg,
                  (char*)Bs + c * 1024);
    }
    __syncthreads();
    bf16x8 af[4], bfr[4];
#pragma unroll
    for (int m = 0; m < 4; ++m)
      af[m] = *(const bf16x8*)(As + (wm * 64 + m * 16 + lq) * 32 + g * 8);
#pragma unroll
    for (int n = 0; n < 4; ++n)
      bfr[n] = *(const bf16x8*)(Bs + (wn * 64 + n * 16 + lq) * 32 + g * 8);
#pragma unroll
    for (int m = 0; m < 4; ++m)
#pragma unroll
      for (int n = 0; n < 4; ++n)
        acc[m][n] = mfma16(af[m], bfr[n], acc[m][n]);
  }

  if (EPI == 0) {
    unsigned short* Qb = (unsigned short*)o0;
    unsigned short* Kb = (unsigned short*)o1;
    unsigned short* Vt = (unsigned short*)o2;
#pragma unroll
    for (int m = 0; m < 4; ++m) {
      const int rbase = row0 + wm * 64 + m * 16 + g * 4;
#pragma unroll
      for (int n = 0; n < 4; ++n) {
        const int col = col0 + wn * 64 + n * 16 + lq;
        const float bi = bias[col];
        const int three = col >> 10;
        const int rem = col & 1023;
        const int h = rem >> 6, d = rem & 63;
#pragma unroll
        for (int r = 0; r < 4; ++r) {
          const int row = rbase + r;
          const int bb = row >> 11, ss = row & 2047;
          const unsigned short bv = f2bf(acc[m][n][r] + bi);
          if (three == 0)
            Qb[(((size_t)(bb * NH + h)) * S + ss) * HD + d] = bv;
          else if (three == 1)
            Kb[(((size_t)(bb * NH + h)) * S + ss) * HD + d] = bv;
          else
            Vt[(((size_t)(bb * NH + h)) * HD + d) * S + ss] = bv;
        }
      }
    }
  } else {
    float* Out = (float*)o0;
#pragma unroll
    for (int m = 0; m < 4; ++m) {
      const int rbase = row0 + wm * 64 + m * 16 + g * 4;
#pragma unroll
      for (int n = 0; n < 4; ++n) {
        const int col = col0 + wn * 64 + n * 16 + lq;
        const float bi = bias[col];
#pragma unroll
        for (int r = 0; r < 4; ++r)
          Out[(size_t)(rbase + r) * N + col] = acc[m][n][r] + bi;
      }
    }
  }
}

// Flash attention v2: swapped QK^T / swapped PV at 32x32x16.
// Block: 4 waves x 32 q-rows = 128 q.  KV tile = 64.  K,Vt in XOR-swizzled LDS.
// Q,K: (b,h,s,d) bf16.  Vt: (b,h,d,s) bf16.  Out: (b,s,h,d) bf16.
__global__ __launch_bounds__(256) void attn_fwd2(
    const unsigned short* __restrict__ Qb, const unsigned short* __restrict__ Kb,
    const unsigned short* __restrict__ Vt, unsigned short* __restrict__ Ao,
    const int* __restrict__ causal_p) {
  __shared__ __align__(16) unsigned short Ks[64 * 64];  // [krow][d], swizzled
  __shared__ __align__(16) unsigned short Vs[64 * 64];  // [d][kcol], swizzled

  const int tid = threadIdx.x, lane = tid & 63, wid = tid >> 6;
  const int cq = lane & 31;         // q column (C/D col = lane&31)
  const int hi = lane >> 5;
  const int id = blockIdx.x;        // 512 blocks
  const int swz = (id & 7) * 64 + (id >> 3);   // XCD-contiguous
  const int bh = swz >> 4;
  const int qt = 15 - (swz & 15);   // heavy tiles first
  const int causal = *causal_p;
  const size_t base  = (size_t)bh * S * HD;
  const size_t vbase = (size_t)bh * HD * S;
  const int qbase = qt * 128 + wid * 32;
  const float CEXP = 0.125f * 1.44269504f;  // 1/sqrt(64) folded into exp2

  // Q as B-operand frags: qf[f] = Q[qbase+cq][f*16 + hi*8 .. +7]
  bf16x8 qf[4];
#pragma unroll
  for (int f = 0; f < 4; ++f)
    qf[f] = *(const bf16x8*)(Qb + base + (size_t)(qbase + cq) * HD + f * 16 + hi * 8);

  float mM = -1e30f, lS = 0.f;
  f32x16 o0 = {}, o1 = {};   // O^T accum: col=q(cq), row=d (+32 for o1)

  const int nkt = causal ? (2 * qt + 2) : (S / 64);
  const int r8 = lane >> 3;
  const int ssl = ((lane & 7) ^ r8) * 8;   // pre-swizzled source slot (elems)

  for (int kt = 0; kt < nkt; ++kt) {
    __syncthreads();
#pragma unroll
    for (int cc = 0; cc < 2; ++cc) {
      const int c = wid * 2 + cc;   // chunks 0..7, 8 rows each
      gload_lds16(Kb + base + (size_t)(kt * 64 + c * 8 + r8) * HD + ssl,
                  (char*)Ks + c * 1024);
      gload_lds16(Vt + vbase + (size_t)(c * 8 + r8) * S + kt * 64 + ssl,
                  (char*)Vs + c * 1024);
    }
    __syncthreads();

    const bool active = (!causal) || (kt * 64 <= qbase + 31);
    if (active) {
      // QK^T swapped: sc = K·Q^T -> D[k][q], col=q
      f32x16 sc0 = {}, sc1 = {};
      const int swb = (cq & 7) << 4;
#pragma unroll
      for (int df = 0; df < 4; ++df) {
        const int colb = (df * 32 + hi * 16) ^ swb;
        bf16x8 k0 = *(const bf16x8*)((const char*)Ks + cq * 128 + colb);
        bf16x8 k1 = *(const bf16x8*)((const char*)Ks + (32 + cq) * 128 + colb);
        sc0 = mfma32(k0, qf[df], sc0);
        sc1 = mfma32(k1, qf[df], sc1);
      }

      const bool diag = causal && (kt * 64 + 63 > qbase);
      if (diag) {
        const int q = qbase + cq;
        const int kb = kt * 64 + 4 * hi;
#pragma unroll
        for (int r = 0; r < 16; ++r) {
          const int kl = (r & 3) + 8 * (r >> 2);
          if (kb + kl > q)      sc0[r] = -1e30f;
          if (kb + 32 + kl > q) sc1[r] = -1e30f;
        }
      }

      // online softmax: in-lane over 32 regs + one lane-pair combine
      float mx = -1e30f;
#pragma unroll
      for (int r = 0; r < 16; ++r) {
        mx = fmaxf(mx, sc0[r]);
        mx = fmaxf(mx, sc1[r]);
      }
      mx = fmaxf(mx, __shfl_xor(mx, 32));
      const float mnew = fmaxf(mM, mx);
      const float alpha = exp2f((mM - mnew) * CEXP);
      mM = mnew;
      float rs = 0.f;
#pragma unroll
      for (int r = 0; r < 16; ++r) {
        sc0[r] = exp2f((sc0[r] - mnew) * CEXP);
        sc1[r] = exp2f((sc1[r] - mnew) * CEXP);
        rs += sc0[r] + sc1[r];
      }
      rs += __shfl_xor(rs, 32);
      lS = lS * alpha + rs;
      o0 *= alpha;
      o1 *= alpha;

      // pack P to bf16 pairs (consecutive k in-lane)
      unsigned w[16];
#pragma unroll
      for (int i = 0; i < 8; ++i) {
        w[i]     = cvt_pk_bf16(sc0[2 * i], sc0[2 * i + 1]);
        w[i + 8] = cvt_pk_bf16(sc1[2 * i], sc1[2 * i + 1]);
      }

      // PV swapped: O^T += Vt·P, B-frag built via lane-pair exchange
#pragma unroll
      for (int m = 0; m < 4; ++m) {
        const unsigned a = w[4 * m], b = w[4 * m + 1], c = w[4 * m + 2], d = w[4 * m + 3];
        const unsigned ra = __shfl_xor((int)(hi ? a : c), 32);
        const unsigned rb = __shfl_xor((int)(hi ? b : d), 32);
        union { unsigned u[4]; bf16x8 v; } pf;
        pf.u[0] = hi ? ra : a;
        pf.u[1] = hi ? rb : b;
        pf.u[2] = hi ? c : ra;
        pf.u[3] = hi ? d : rb;
        const int colb = (m * 32 + hi * 16) ^ swb;
        bf16x8 v0 = *(const bf16x8*)((const char*)Vs + cq * 128 + colb);
        bf16x8 v1 = *(const bf16x8*)((const char*)Vs + (32 + cq) * 128 + colb);
        o0 = mfma32(v0, pf.v, o0);
        o1 = mfma32(v1, pf.v, o1);
      }
    }
  }

  // epilogue: O[q][d] = O^T/lS, write (b, s, h, d)
  const int bb2 = bh >> 4, hh = bh & 15;
  unsigned short* orow = Ao + (((size_t)bb2 * S + (qbase + cq)) * NH + hh) * HD;
  const float inv = 1.0f / lS;
#pragma unroll
  for (int i = 0; i < 4; ++i) {
    ushort4 u0, u1;
    u0.x = f2bf(o0[4 * i + 0] * inv); u0.y = f2bf(o0[4 * i + 1] * inv);
    u0.z = f2bf(o0[4 * i + 2] * inv); u0.w = f2bf(o0[4 * i + 3] * inv);
    u1.x = f2bf(o1[4 * i + 0] * inv); u1.y = f2bf(o1[4 * i + 1] * inv);
    u1.z = f2bf(o1[4 * i + 2] * inv); u1.w = f2bf(o1[4 * i + 3] * inv);
    *(ushort4*)(orow + i * 8 + 4 * hi) = u0;
    *(ushort4*)(orow + 32 + i * 8 + 4 * hi) = u1;
  }
}

extern "C" void kernel_launch(void* const* d_in, const int* in_sizes, int n_in,
                              void* d_out, int out_size, void* d_ws, size_t ws_size,
                              hipStream_t stream) {
  const float* x     = (const float*)d_in[0];
  const float* w_qkv = (const float*)d_in[1];
  const float* b_qkv = (const float*)d_in[2];
  const float* w_out = (const float*)d_in[3];
  const float* b_out = (const float*)d_in[4];
  const int*   causal = (const int*)d_in[5];

  char* ws = (char*)d_ws;
  unsigned short* xb    = (unsigned short*)(ws);
  unsigned short* wqkvb = (unsigned short*)(ws + 8388608);
  unsigned short* wob   = (unsigned short*)(ws + 14680064);
  unsigned short* Qb    = (unsigned short*)(ws + 16777216);
  unsigned short* Kb    = (unsigned short*)(ws + 25165824);
  unsigned short* Vtb   = (unsigned short*)(ws + 33554432);
  unsigned short* attnb = (unsigned short*)(ws + 41943040);

  convert_bf16<<<1024, 256, 0, stream>>>(x, xb, (BB * S * E) / 4);
  convert_bf16<<<1024, 256, 0, stream>>>(w_qkv, wqkvb, (3 * E * E) / 4);
  convert_bf16<<<512, 256, 0, stream>>>(w_out, wob, (E * E) / 4);

  gemm_bt<0><<<dim3(3 * E / 128, MR / 128), 256, 0, stream>>>(
      xb, wqkvb, b_qkv, Qb, Kb, Vtb, MR, 3 * E, E);

  attn_fwd2<<<512, 256, 0, stream>>>(Qb, Kb, Vtb, attnb, causal);

  gemm_bt<1><<<dim3(E / 128, MR / 128), 256, 0, stream>>>(
      attnb, wob, b_out, d_out, nullptr, nullptr, MR, E, E);
}